// Round 7
// baseline (864.979 us; speedup 1.0000x reference)
//
#include <hip/hip_runtime.h>

#define KD 192
#define H6 6

typedef __attribute__((ext_vector_type(8))) short bf16x8;
typedef __attribute__((ext_vector_type(4))) float f32x4;

__device__ __forceinline__ unsigned short f2bf(float f) {
  unsigned u = __float_as_uint(f);
  u += 0x7FFFu + ((u >> 16) & 1u);
  return (unsigned short)(u >> 16);
}

// ---------------- bias table ----------------
__global__ void bias_k(const float* __restrict__ tab, float* __restrict__ biasw) {
  int t = blockIdx.x * 256 + threadIdx.x;
  if (t >= H6 * 64 * 64) return;
  int h = t >> 12, rem = t & 4095, i = rem >> 6, j = rem & 63;
  int idx = ((i >> 3) - (j >> 3) + 7) * 15 + ((i & 7) - (j & 7) + 7);
  biasw[t] = tab[idx * H6 + h];
}

// ---------------- weight pre-conversion (f32 -> bf16), one dispatch ----------------
__global__ void convert_k(
    const float* __restrict__ sa_qkv_w, const float* __restrict__ sa_ct_w,
    const float* __restrict__ sa_cr_w, const float* __restrict__ ca_q_w,
    const float* __restrict__ ca_kv_w, const float* __restrict__ ca_ct_w,
    const float* __restrict__ ca_cr_w, const float* __restrict__ proj_sa_w,
    const float* __restrict__ proj_ca_w,
    const float* __restrict__ ca_q_b, const float* __restrict__ ca_kv_b,
    unsigned short* __restrict__ wqkv, unsigned short* __restrict__ wct_sa,
    unsigned short* __restrict__ wcr_sa, unsigned short* __restrict__ wca,
    unsigned short* __restrict__ wct_ca, unsigned short* __restrict__ wcr_ca,
    unsigned short* __restrict__ wpsa, unsigned short* __restrict__ wpca,
    float* __restrict__ bca)
{
  int t = blockIdx.x * 256 + threadIdx.x;
  if (t < 110592) {                 // weight conversion, float4 units
    int i = t << 2;
    const float* s; unsigned short* d;
    if (i < 110592)      { s = sa_qkv_w + i;            d = wqkv + i; }
    else if (i < 147456) { s = sa_ct_w + (i - 110592);  d = wct_sa + (i - 110592); }
    else if (i < 184320) { s = sa_cr_w + (i - 147456);  d = wcr_sa + (i - 147456); }
    else if (i < 221184) { s = ca_q_w + (i - 184320);   d = wca + (i - 184320); }
    else if (i < 294912) { s = ca_kv_w + (i - 221184);  d = wca + 36864 + (i - 221184); }
    else if (i < 331776) { s = ca_ct_w + (i - 294912);  d = wct_ca + (i - 294912); }
    else if (i < 368640) { s = ca_cr_w + (i - 331776);  d = wcr_ca + (i - 331776); }
    else if (i < 405504) { s = proj_sa_w + (i - 368640); d = wpsa + (i - 368640); }
    else                 { s = proj_ca_w + (i - 405504); d = wpca + (i - 405504); }
    float4 v = *(const float4*)s;
    ushort4 p;
    p.x = f2bf(v.x); p.y = f2bf(v.y); p.z = f2bf(v.z); p.w = f2bf(v.w);
    *(ushort4*)d = p;
  } else if (t < 110592 + 144) {    // combined CA bias (f32 copy)
    int i = (t - 110592) << 2;
    const float* s = (i < 192) ? (ca_q_b + i) : (ca_kv_b + (i - 192));
    *(float4*)(bca + i) = *(const float4*)s;
  }
}

// ---------------- fused enhance + qkv (restructured) ----------------
// One block = one (window, path). 4 waves, each owns a 32x32 quadrant.
// A/enh fragments live in registers (af[2][6]); AE LDS buffer holds A first,
// then is overwritten by enh. W tiles are reg-prefetched (global->VGPR before
// MFMA, ds_write after barrier). LDS = 2 x 25.6 KB -> 3 blocks/CU.
struct FQArgs {
  const unsigned short* Wc[4];
  const unsigned short* Wq[4];
  const float* bias[4];
  unsigned short* dq[4];
  unsigned short* dk[4];
  unsigned short* dv[4];
};

__global__ __launch_bounds__(256, 3) void fqkv_k(
    const float* __restrict__ x, const float* __restrict__ y,
    const float* __restrict__ sap, const float* __restrict__ cap,
    FQArgs args, float SC)
{
  __shared__ short AE[64][200];
  __shared__ short Wl[64][200];
  const int tid = threadIdx.x;
  const int mblk = blockIdx.x, z = blockIdx.y;
  const int row = tid >> 2, cb = (tid & 3) * 48;
  const float* A    = (z & 1) ? x : y;
  const float* resd = (z & 1) ? y : x;
  const float sc = (z < 2) ? *sap : *cap;

  float4 wpf[6];
  {  // stage A (f32->bf16) into AE; preload W tile 0 -> regs -> Wl
    const float* ap = A + ((long)mblk * 64 + row) * KD + cb;
    const unsigned short* wp = args.Wc[z] + (long)row * KD + cb;
#pragma unroll
    for (int j = 0; j < 6; ++j) wpf[j] = *(const float4*)(wp + 8 * j);
#pragma unroll
    for (int j = 0; j < 12; ++j) {
      float4 v = *(const float4*)(ap + 4 * j);
      ushort4 p;
      p.x = f2bf(v.x); p.y = f2bf(v.y); p.z = f2bf(v.z); p.w = f2bf(v.w);
      *(ushort4*)&AE[row][cb + 4 * j] = p;
    }
#pragma unroll
    for (int j = 0; j < 6; ++j) *(float4*)&Wl[row][cb + 8 * j] = wpf[j];
  }
  __syncthreads();

  const int lane = tid & 63, wv = tid >> 6;
  const int qn = lane & 15, g = lane >> 4;
  const int rbase = (wv & 1) * 32, cbase = (wv >> 1) * 32;
  const f32x4 zero = {0.f, 0.f, 0.f, 0.f};

  // A fragments -> registers (AE's A content is dead after this)
  bf16x8 af[2][6];
#pragma unroll
  for (int im = 0; im < 2; ++im)
#pragma unroll
    for (int ks = 0; ks < 6; ++ks)
      af[im][ks] = *(const bf16x8*)&AE[rbase + 16 * im + qn][32 * ks + 8 * g];

  // ---- phase 2: 3 enhance tiles, accumulators kept across tiles ----
  f32x4 acc2[3][2][2];
#pragma unroll
  for (int t = 0; t < 3; ++t)
#pragma unroll
    for (int im = 0; im < 2; ++im)
#pragma unroll
      for (int in = 0; in < 2; ++in) acc2[t][im][in] = zero;

#pragma unroll
  for (int t = 0; t < 3; ++t) {
    {  // prefetch next W tile (t==2 -> Wq tile 0)
      const unsigned short* ns = (t < 2) ? (args.Wc[z] + (long)(t + 1) * 12288)
                                         : args.Wq[z];
      const unsigned short* wp = ns + (long)row * KD + cb;
#pragma unroll
      for (int j = 0; j < 6; ++j) wpf[j] = *(const float4*)(wp + 8 * j);
    }
#pragma unroll
    for (int ks = 0; ks < 6; ++ks) {
      bf16x8 wf0 = *(const bf16x8*)&Wl[cbase + qn][32 * ks + 8 * g];
      bf16x8 wf1 = *(const bf16x8*)&Wl[cbase + 16 + qn][32 * ks + 8 * g];
      acc2[t][0][0] = __builtin_amdgcn_mfma_f32_16x16x32_bf16(af[0][ks], wf0, acc2[t][0][0], 0, 0, 0);
      acc2[t][1][0] = __builtin_amdgcn_mfma_f32_16x16x32_bf16(af[1][ks], wf0, acc2[t][1][0], 0, 0, 0);
      acc2[t][0][1] = __builtin_amdgcn_mfma_f32_16x16x32_bf16(af[0][ks], wf1, acc2[t][0][1], 0, 0, 0);
      acc2[t][1][1] = __builtin_amdgcn_mfma_f32_16x16x32_bf16(af[1][ks], wf1, acc2[t][1][1], 0, 0, 0);
    }
    __syncthreads();                       // all waves done reading Wl
#pragma unroll
    for (int j = 0; j < 6; ++j) *(float4*)&Wl[row][cb + 8 * j] = wpf[j];
    __syncthreads();                       // next tile ready
  }

  // ---- enh transition: write El over AE, reload fragments ----
#pragma unroll
  for (int ct = 0; ct < 3; ++ct)
#pragma unroll
    for (int im = 0; im < 2; ++im)
#pragma unroll
      for (int in = 0; in < 2; ++in) {
        const int c = ct * 64 + cbase + 16 * in + qn;
        const int rl = rbase + 16 * im + 4 * g;
#pragma unroll
        for (int r = 0; r < 4; ++r)
          AE[rl + r][c] = f2bf(resd[((long)mblk * 64 + rl + r) * KD + c] +
                               sc * acc2[ct][im][in][r]);
      }
  __syncthreads();
#pragma unroll
  for (int im = 0; im < 2; ++im)
#pragma unroll
    for (int ks = 0; ks < 6; ++ks)
      af[im][ks] = *(const bf16x8*)&AE[rbase + 16 * im + qn][32 * ks + 8 * g];

  // ---- phase 3: 9 qkv tiles (Wl already holds Wq tile 0) ----
  for (int wt = 0; wt < 9; ++wt) {
    if (wt < 8) {
      const unsigned short* wp = args.Wq[z] + (long)(wt + 1) * 12288 + (long)row * KD + cb;
#pragma unroll
      for (int j = 0; j < 6; ++j) wpf[j] = *(const float4*)(wp + 8 * j);
    }
    f32x4 acc[2][2] = {{zero, zero}, {zero, zero}};
#pragma unroll
    for (int ks = 0; ks < 6; ++ks) {
      bf16x8 wf0 = *(const bf16x8*)&Wl[cbase + qn][32 * ks + 8 * g];
      bf16x8 wf1 = *(const bf16x8*)&Wl[cbase + 16 + qn][32 * ks + 8 * g];
      acc[0][0] = __builtin_amdgcn_mfma_f32_16x16x32_bf16(af[0][ks], wf0, acc[0][0], 0, 0, 0);
      acc[1][0] = __builtin_amdgcn_mfma_f32_16x16x32_bf16(af[1][ks], wf0, acc[1][0], 0, 0, 0);
      acc[0][1] = __builtin_amdgcn_mfma_f32_16x16x32_bf16(af[0][ks], wf1, acc[0][1], 0, 0, 0);
      acc[1][1] = __builtin_amdgcn_mfma_f32_16x16x32_bf16(af[1][ks], wf1, acc[1][1], 0, 0, 0);
    }
#pragma unroll
    for (int im = 0; im < 2; ++im)
#pragma unroll
      for (int in = 0; in < 2; ++in) {
        const int cg = wt * 64 + cbase + 16 * in + qn;
        const int idx = (cg >= 384) ? 2 : ((cg >= 192) ? 1 : 0);
        const int cc = cg - idx * KD;
        const int h = cc >> 5, d = cc & 31;
        const float bv = args.bias[z][cg];
        const long bwh = (long)mblk * H6 + h;
        const int rl = rbase + 16 * im + 4 * g;
        if (idx < 2) {
          const float sca = idx ? 1.f : SC;
          unsigned short* dst = idx ? args.dk[z] : args.dq[z];
#pragma unroll
          for (int r = 0; r < 4; ++r)
            dst[(bwh * 64 + rl + r) * 32 + d] = f2bf((acc[im][in][r] + bv) * sca);
        } else {  // v transposed: [b][h][d][tok]
          ushort4 p;
          p.x = f2bf(acc[im][in][0] + bv);
          p.y = f2bf(acc[im][in][1] + bv);
          p.z = f2bf(acc[im][in][2] + bv);
          p.w = f2bf(acc[im][in][3] + bv);
          *(ushort4*)&args.dv[z][(bwh * 32 + d) * 64 + rl] = p;
        }
      }
    if (wt < 8) {
      __syncthreads();
#pragma unroll
      for (int j = 0; j < 6; ++j) *(float4*)&Wl[row][cb + 8 * j] = wpf[j];
      __syncthreads();
    }
  }
}

// ---------------- proj: stage A once, loop 3 W col-tiles; grid (B, 4) ----------------
struct ProjArgs {
  const unsigned short* A[4];
  const unsigned short* W[4];
  const float* bias[4];
  float* o[4];
  long wstride[4];
};

__global__ __launch_bounds__(256) void proj_k(ProjArgs args)
{
  __shared__ short Al[64][200], Wl[64][200];
  const int tid = threadIdx.x;
  const int mblk = blockIdx.x, z = blockIdx.y;
  const int row = tid >> 2, cb = (tid & 3) * 48;
  {
    const unsigned short* A = args.A[z] + ((long)mblk * 64 + row) * KD + cb;
#pragma unroll
    for (int j = 0; j < 6; ++j)
      *(float4*)&Al[row][cb + 8 * j] = *(const float4*)(A + 8 * j);
  }
  const int lane = tid & 63, wv = tid >> 6;
  const int qn = lane & 15, g = lane >> 4;
  const int mloc = 16 * wv + 4 * g;
  const f32x4 zero = {0.f, 0.f, 0.f, 0.f};
  float* fo = args.o[z] + (long)mblk * args.wstride[z];

  for (int ct = 0; ct < 3; ++ct) {
    {
      const unsigned short* Wp = args.W[z] + ((long)ct * 64 + row) * KD + cb;
#pragma unroll
      for (int j = 0; j < 6; ++j)
        *(float4*)&Wl[row][cb + 8 * j] = *(const float4*)(Wp + 8 * j);
    }
    __syncthreads();
    f32x4 acc[4];
#pragma unroll
    for (int nt = 0; nt < 4; ++nt) acc[nt] = zero;
#pragma unroll
    for (int ks = 0; ks < 6; ++ks) {
      bf16x8 a = *(const bf16x8*)&Al[16 * wv + qn][32 * ks + 8 * g];
#pragma unroll
      for (int nt = 0; nt < 4; ++nt) {
        bf16x8 bfr = *(const bf16x8*)&Wl[16 * nt + qn][32 * ks + 8 * g];
        acc[nt] = __builtin_amdgcn_mfma_f32_16x16x32_bf16(a, bfr, acc[nt], 0, 0, 0);
      }
    }
#pragma unroll
    for (int nt = 0; nt < 4; ++nt) {
      const int c = ct * 64 + 16 * nt + qn;
      const float bv = args.bias[z][c];
#pragma unroll
      for (int r = 0; r < 4; ++r)
        fo[(long)(mloc + r) * KD + c] = acc[nt][r] + bv;
    }
    __syncthreads();
  }
}

// ---------------- attention: 4 waves/block, each wave = 32 q-rows of one (b,h) ----------------
__device__ __forceinline__ void softmax_rows2(f32x4 (&S)[4][2]) {
#pragma unroll
  for (int nt = 0; nt < 2; ++nt) {
    float mx = -3.0e38f;
#pragma unroll
    for (int mt = 0; mt < 4; ++mt)
#pragma unroll
      for (int r = 0; r < 4; ++r) mx = fmaxf(mx, S[mt][nt][r]);
    mx = fmaxf(mx, __shfl_xor(mx, 16));
    mx = fmaxf(mx, __shfl_xor(mx, 32));
    float sm = 0.f;
#pragma unroll
    for (int mt = 0; mt < 4; ++mt)
#pragma unroll
      for (int r = 0; r < 4; ++r) {
        float p = __expf(S[mt][nt][r] - mx);
        S[mt][nt][r] = p;
        sm += p;
      }
    sm += __shfl_xor(sm, 16);
    sm += __shfl_xor(sm, 32);
    const float inv = 1.f / sm;
#pragma unroll
    for (int mt = 0; mt < 4; ++mt)
#pragma unroll
      for (int r = 0; r < 4; ++r) S[mt][nt][r] *= inv;
  }
}

__device__ __forceinline__ void diff_attn32(
    const unsigned short* __restrict__ qb, const unsigned short* __restrict__ kb,
    const unsigned short* __restrict__ vTb, long pstride,
    const float* __restrict__ bh, float lam,
    unsigned short* __restrict__ o_t, unsigned short* __restrict__ o_r,
    long base, int b, int h, int qoff, int qn, int g,
    short (*Pl)[32][72])
{
  f32x4 st[4][2], sr[4][2];
#pragma unroll
  for (int mt = 0; mt < 4; ++mt)
#pragma unroll
    for (int nt = 0; nt < 2; ++nt) {
      f32x4 bv = *(const f32x4*)&bh[(qoff + 16 * nt + qn) * 64 + 16 * mt + 4 * g];
      st[mt][nt] = bv;
      sr[mt][nt] = bv;
    }
  {
    bf16x8 ka[4], qv[2];
#pragma unroll
    for (int mt = 0; mt < 4; ++mt)
      ka[mt] = *(const bf16x8*)&kb[base + (16 * mt + qn) * 32 + 8 * g];
#pragma unroll
    for (int nt = 0; nt < 2; ++nt)
      qv[nt] = *(const bf16x8*)&qb[base + (qoff + 16 * nt + qn) * 32 + 8 * g];
#pragma unroll
    for (int mt = 0; mt < 4; ++mt)
#pragma unroll
      for (int nt = 0; nt < 2; ++nt)
        st[mt][nt] = __builtin_amdgcn_mfma_f32_16x16x32_bf16(ka[mt], qv[nt], st[mt][nt], 0, 0, 0);
#pragma unroll
    for (int mt = 0; mt < 4; ++mt)
      ka[mt] = *(const bf16x8*)&kb[pstride + base + (16 * mt + qn) * 32 + 8 * g];
#pragma unroll
    for (int nt = 0; nt < 2; ++nt)
      qv[nt] = *(const bf16x8*)&qb[pstride + base + (qoff + 16 * nt + qn) * 32 + 8 * g];
#pragma unroll
    for (int mt = 0; mt < 4; ++mt)
#pragma unroll
      for (int nt = 0; nt < 2; ++nt)
        sr[mt][nt] = __builtin_amdgcn_mfma_f32_16x16x32_bf16(ka[mt], qv[nt], sr[mt][nt], 0, 0, 0);
  }
  softmax_rows2(st);
  softmax_rows2(sr);
#pragma unroll
  for (int mt = 0; mt < 4; ++mt)
#pragma unroll
    for (int nt = 0; nt < 2; ++nt) {
      ushort4 pt, pr;
#pragma unroll
      for (int r = 0; r < 4; ++r) {
        float a = st[mt][nt][r], rr = sr[mt][nt][r];
        ((unsigned short*)&pt)[r] = f2bf(a - lam * rr);
        ((unsigned short*)&pr)[r] = f2bf(rr - lam * a);
      }
      *(ushort4*)&Pl[0][16 * nt + qn][16 * mt + 4 * g] = pt;
      *(ushort4*)&Pl[1][16 * nt + qn][16 * mt + 4 * g] = pr;
    }
  const f32x4 zero = {0.f, 0.f, 0.f, 0.f};
#pragma unroll
  for (int p = 0; p < 2; ++p) {
    const unsigned short* vv = p ? (vTb + pstride) : vTb;
    unsigned short* outp = p ? o_r : o_t;
    f32x4 oa[2][2];
#pragma unroll
    for (int i = 0; i < 2; ++i)
#pragma unroll
      for (int nt = 0; nt < 2; ++nt) oa[i][nt] = zero;
#pragma unroll
    for (int ks = 0; ks < 2; ++ks) {
      bf16x8 va0 = *(const bf16x8*)&vv[base + (0 + qn) * 64 + 32 * ks + 8 * g];
      bf16x8 va1 = *(const bf16x8*)&vv[base + (16 + qn) * 64 + 32 * ks + 8 * g];
#pragma unroll
      for (int nt = 0; nt < 2; ++nt) {
        bf16x8 pb = *(const bf16x8*)&Pl[p][16 * nt + qn][32 * ks + 8 * g];
        oa[0][nt] = __builtin_amdgcn_mfma_f32_16x16x32_bf16(va0, pb, oa[0][nt], 0, 0, 0);
        oa[1][nt] = __builtin_amdgcn_mfma_f32_16x16x32_bf16(va1, pb, oa[1][nt], 0, 0, 0);
      }
    }
#pragma unroll
    for (int d16 = 0; d16 < 2; ++d16)
#pragma unroll
      for (int nt = 0; nt < 2; ++nt) {
        const int q = qoff + 16 * nt + qn;
        ushort4 pk;
        pk.x = f2bf(oa[d16][nt][0]); pk.y = f2bf(oa[d16][nt][1]);
        pk.z = f2bf(oa[d16][nt][2]); pk.w = f2bf(oa[d16][nt][3]);
        *(ushort4*)&outp[((long)b * 64 + q) * KD + h * 32 + 16 * d16 + 4 * g] = pk;
      }
  }
}

__global__ __launch_bounds__(256) void attn_k(
    const unsigned short* __restrict__ saq, const unsigned short* __restrict__ sak,
    const unsigned short* __restrict__ savT,
    const unsigned short* __restrict__ caq, const unsigned short* __restrict__ cak,
    const unsigned short* __restrict__ cavT,
    const float* __restrict__ biasw, const float* __restrict__ lsp,
    const float* __restrict__ lcp,
    unsigned short* __restrict__ o0, unsigned short* __restrict__ o1,
    unsigned short* __restrict__ o2, unsigned short* __restrict__ o3,
    long pstride)
{
  __shared__ short Pl[4][2][32][72];   // [wave][path][q][k] — per-wave private, no barriers
  const int wv = threadIdx.x >> 6, lane = threadIdx.x & 63;
  const int qn = lane & 15, g = lane >> 4;
  const int qoff = (wv & 1) * 32;
  const int wh = blockIdx.x * 2 + (wv >> 1);
  const int b = wh / H6, h = wh - b * H6;
  const float* bh = biasw + (long)h * 4096;
  const long base = (long)wh * 2048;
  float ls = 1.f / (1.f + __expf(-*lsp));
  ls = fminf(fmaxf(ls, 0.01f), 0.99f);
  float lc = 1.f / (1.f + __expf(-*lcp));
  lc = fminf(fmaxf(lc, 0.01f), 0.99f);
  diff_attn32(saq, sak, savT, pstride, bh, ls, o0, o1, base, b, h, qoff, qn, g, Pl[wv]);
  diff_attn32(caq, cak, cavT, pstride, bh, lc, o2, o3, base, b, h, qoff, qn, g, Pl[wv]);
}

// ---------------- host ----------------
extern "C" void kernel_launch(void* const* d_in, const int* in_sizes, int n_in,
                              void* d_out, int out_size, void* d_ws, size_t ws_size,
                              hipStream_t stream)
{
  const float* x         = (const float*)d_in[0];
  const float* y         = (const float*)d_in[1];
  const float* sa_qkv_w  = (const float*)d_in[2];
  const float* sa_qkv_b  = (const float*)d_in[3];
  const float* sa_ct_w   = (const float*)d_in[4];
  const float* sa_cr_w   = (const float*)d_in[5];
  const float* ca_q_w    = (const float*)d_in[6];
  const float* ca_q_b    = (const float*)d_in[7];
  const float* ca_kv_w   = (const float*)d_in[8];
  const float* ca_kv_b   = (const float*)d_in[9];
  const float* ca_ct_w   = (const float*)d_in[10];
  const float* ca_cr_w   = (const float*)d_in[11];
  const float* rpb       = (const float*)d_in[12];
  const float* proj_sa_w = (const float*)d_in[13];
  const float* proj_sa_b = (const float*)d_in[14];
  const float* proj_ca_w = (const float*)d_in[15];
  const float* proj_ca_b = (const float*)d_in[16];
  const float* lam_sa_p  = (const float*)d_in[17];
  const float* lam_ca_p  = (const float*)d_in[18];
  const float* sa_enh_p  = (const float*)d_in[19];
  const float* ca_enh_p  = (const float*)d_in[20];
  float* out = (float*)d_out;

  const int M = in_sizes[0] / KD;            // 65536
  const int B = M / 64;                      // 1024
  const long pstride = (long)B * H6 * 2048;  // 12,582,912 elements

  char* ws = (char*)d_ws;
  float* biasw = (float*)ws;                               // 98304 B
  float* bca = (float*)(ws + 98304);                       // 2304 B
  unsigned short* wqkv   = (unsigned short*)(ws + 100864); // 221184 B
  unsigned short* wca    = (unsigned short*)(ws + 322048); // 221184 B
  unsigned short* wct_sa = (unsigned short*)(ws + 543232);
  unsigned short* wcr_sa = (unsigned short*)(ws + 616960);
  unsigned short* wct_ca = (unsigned short*)(ws + 690688);
  unsigned short* wcr_ca = (unsigned short*)(ws + 764416);
  unsigned short* wpsa   = (unsigned short*)(ws + 838144);
  unsigned short* wpca   = (unsigned short*)(ws + 911872);
  long off = 1048576;
  unsigned short* ob0 = (unsigned short*)(ws + off); off += (long)M * KD * 2;  // attn outputs
  unsigned short* ob1 = (unsigned short*)(ws + off); off += (long)M * KD * 2;
  unsigned short* ob2 = (unsigned short*)(ws + off); off += (long)M * KD * 2;
  unsigned short* ob3 = (unsigned short*)(ws + off); off += (long)M * KD * 2;
  unsigned short* caq  = (unsigned short*)(ws + off); off += pstride * 4;
  unsigned short* cak  = (unsigned short*)(ws + off); off += pstride * 4;
  unsigned short* cavT = (unsigned short*)(ws + off); off += pstride * 4;
  unsigned short* saq  = (unsigned short*)d_out;   // SA qkv staged in d_out (151 MB)
  unsigned short* sak  = saq + 2 * pstride;
  unsigned short* savT = sak + 2 * pstride;

  const float SC = 0.17677669529663687f;  // 32^-0.5

  convert_k<<<dim3(433), dim3(256), 0, stream>>>(
      sa_qkv_w, sa_ct_w, sa_cr_w, ca_q_w, ca_kv_w, ca_ct_w, ca_cr_w,
      proj_sa_w, proj_ca_w, ca_q_b, ca_kv_b,
      wqkv, wct_sa, wcr_sa, wca, wct_ca, wcr_ca, wpsa, wpca, bca);
  bias_k<<<dim3(96), dim3(256), 0, stream>>>(rpb, biasw);

  FQArgs fa;
  fa.Wc[0] = wcr_sa; fa.Wc[1] = wct_sa; fa.Wc[2] = wcr_ca; fa.Wc[3] = wct_ca;
  fa.Wq[0] = wqkv;   fa.Wq[1] = wqkv;   fa.Wq[2] = wca;    fa.Wq[3] = wca;
  fa.bias[0] = sa_qkv_b; fa.bias[1] = sa_qkv_b; fa.bias[2] = bca; fa.bias[3] = bca;
  fa.dq[0] = saq;  fa.dq[1] = saq + pstride;  fa.dq[2] = caq;  fa.dq[3] = caq + pstride;
  fa.dk[0] = sak;  fa.dk[1] = sak + pstride;  fa.dk[2] = cak;  fa.dk[3] = cak + pstride;
  fa.dv[0] = savT; fa.dv[1] = savT + pstride; fa.dv[2] = cavT; fa.dv[3] = cavT + pstride;
  fqkv_k<<<dim3(B, 4), dim3(256), 0, stream>>>(x, y, sa_enh_p, ca_enh_p, fa, SC);

  attn_k<<<dim3(B * H6 / 2), dim3(256), 0, stream>>>(saq, sak, savT, caq, cak, cavT,
                                                     biasw, lam_sa_p, lam_ca_p,
                                                     ob0, ob1, ob2, ob3, pstride);

  ProjArgs pa;
  pa.A[0] = ob0; pa.A[1] = ob1; pa.A[2] = ob2; pa.A[3] = ob3;
  pa.W[0] = wpsa; pa.W[1] = wpsa; pa.W[2] = wpca; pa.W[3] = wpca;
  pa.bias[0] = proj_sa_b; pa.bias[1] = proj_sa_b; pa.bias[2] = proj_ca_b; pa.bias[3] = proj_ca_b;
  pa.o[0] = out;                       pa.wstride[0] = 12288;
  pa.o[1] = out + (long)B * 12288;     pa.wstride[1] = 12288;
  pa.o[2] = out + (long)2 * B * 12288; pa.wstride[2] = 24576;
  pa.o[3] = out + (long)2 * B * 12288 + 12288; pa.wstride[3] = 24576;
  proj_k<<<dim3(B, 4), dim3(256), 0, stream>>>(pa);
}

// Round 8
// 636.403 us; speedup vs baseline: 1.3592x; 1.3592x over previous
//
#include <hip/hip_runtime.h>

#define KD 192
#define H6 6

typedef __attribute__((ext_vector_type(8))) short bf16x8;
typedef __attribute__((ext_vector_type(4))) float f32x4;

__device__ __forceinline__ unsigned short f2bf(float f) {
  unsigned u = __float_as_uint(f);
  u += 0x7FFFu + ((u >> 16) & 1u);
  return (unsigned short)(u >> 16);
}

// ---------------- bias table ----------------
__global__ void bias_k(const float* __restrict__ tab, float* __restrict__ biasw) {
  int t = blockIdx.x * 256 + threadIdx.x;
  if (t >= H6 * 64 * 64) return;
  int h = t >> 12, rem = t & 4095, i = rem >> 6, j = rem & 63;
  int idx = ((i >> 3) - (j >> 3) + 7) * 15 + ((i & 7) - (j & 7) + 7);
  biasw[t] = tab[idx * H6 + h];
}

// ---------------- weight pre-conversion (f32 -> bf16), one dispatch ----------------
__global__ void convert_k(
    const float* __restrict__ sa_qkv_w, const float* __restrict__ sa_ct_w,
    const float* __restrict__ sa_cr_w, const float* __restrict__ ca_q_w,
    const float* __restrict__ ca_kv_w, const float* __restrict__ ca_ct_w,
    const float* __restrict__ ca_cr_w, const float* __restrict__ proj_sa_w,
    const float* __restrict__ proj_ca_w,
    const float* __restrict__ ca_q_b, const float* __restrict__ ca_kv_b,
    unsigned short* __restrict__ wqkv, unsigned short* __restrict__ wct_sa,
    unsigned short* __restrict__ wcr_sa, unsigned short* __restrict__ wca,
    unsigned short* __restrict__ wct_ca, unsigned short* __restrict__ wcr_ca,
    unsigned short* __restrict__ wpsa, unsigned short* __restrict__ wpca,
    float* __restrict__ bca)
{
  int t = blockIdx.x * 256 + threadIdx.x;
  if (t < 110592) {                 // weight conversion, float4 units
    int i = t << 2;
    const float* s; unsigned short* d;
    if (i < 110592)      { s = sa_qkv_w + i;            d = wqkv + i; }
    else if (i < 147456) { s = sa_ct_w + (i - 110592);  d = wct_sa + (i - 110592); }
    else if (i < 184320) { s = sa_cr_w + (i - 147456);  d = wcr_sa + (i - 147456); }
    else if (i < 221184) { s = ca_q_w + (i - 184320);   d = wca + (i - 184320); }
    else if (i < 294912) { s = ca_kv_w + (i - 221184);  d = wca + 36864 + (i - 221184); }
    else if (i < 331776) { s = ca_ct_w + (i - 294912);  d = wct_ca + (i - 294912); }
    else if (i < 368640) { s = ca_cr_w + (i - 331776);  d = wcr_ca + (i - 331776); }
    else if (i < 405504) { s = proj_sa_w + (i - 368640); d = wpsa + (i - 368640); }
    else                 { s = proj_ca_w + (i - 405504); d = wpca + (i - 405504); }
    float4 v = *(const float4*)s;
    ushort4 p;
    p.x = f2bf(v.x); p.y = f2bf(v.y); p.z = f2bf(v.z); p.w = f2bf(v.w);
    *(ushort4*)d = p;
  } else if (t < 110592 + 144) {    // combined CA bias (f32 copy)
    int i = (t - 110592) << 2;
    const float* s = (i < 192) ? (ca_q_b + i) : (ca_kv_b + (i - 192));
    *(float4*)(bca + i) = *(const float4*)s;
  }
}

// ---------------- fused enhance + qkv (R6-proven version) ----------------
struct FQArgs {
  const unsigned short* Wc[4];
  const unsigned short* Wq[4];
  const float* bias[4];
  unsigned short* dq[4];
  unsigned short* dk[4];
  unsigned short* dv[4];
};

__global__ __launch_bounds__(256) void fqkv_k(
    const float* __restrict__ x, const float* __restrict__ y,
    const float* __restrict__ sap, const float* __restrict__ cap,
    FQArgs args, float SC)
{
  __shared__ short Al[64][200], Wl[64][200], El[64][200];
  const int tid = threadIdx.x;
  const int mblk = blockIdx.x, z = blockIdx.y;
  const int row = tid >> 2, cb = (tid & 3) * 48;
  const float* A    = (z & 1) ? x : y;
  const float* resd = (z & 1) ? y : x;
  const float sc = (z < 2) ? *sap : *cap;

  {  // phase 1
    const float* ap = A + ((long)mblk * 64 + row) * KD + cb;
#pragma unroll
    for (int j = 0; j < 12; ++j) {
      float4 v = *(const float4*)(ap + 4 * j);
      ushort4 p;
      p.x = f2bf(v.x); p.y = f2bf(v.y); p.z = f2bf(v.z); p.w = f2bf(v.w);
      *(ushort4*)&Al[row][cb + 4 * j] = p;
    }
  }
  const int lane = tid & 63, wv = tid >> 6;
  const int qn = lane & 15, g = lane >> 4;
  const int mloc = 16 * wv + 4 * g;
  const f32x4 zero = {0.f, 0.f, 0.f, 0.f};

  // phase 2: enh into El
  for (int ct = 0; ct < 3; ++ct) {
    {
      const unsigned short* Wp = args.Wc[z] + ((long)ct * 64 + row) * KD + cb;
#pragma unroll
      for (int j = 0; j < 6; ++j)
        *(float4*)&Wl[row][cb + 8 * j] = *(const float4*)(Wp + 8 * j);
    }
    __syncthreads();
    f32x4 acc[4];
#pragma unroll
    for (int nt = 0; nt < 4; ++nt) acc[nt] = zero;
#pragma unroll
    for (int ks = 0; ks < 6; ++ks) {
      bf16x8 a = *(const bf16x8*)&Al[16 * wv + qn][32 * ks + 8 * g];
#pragma unroll
      for (int nt = 0; nt < 4; ++nt) {
        bf16x8 bfr = *(const bf16x8*)&Wl[16 * nt + qn][32 * ks + 8 * g];
        acc[nt] = __builtin_amdgcn_mfma_f32_16x16x32_bf16(a, bfr, acc[nt], 0, 0, 0);
      }
    }
#pragma unroll
    for (int nt = 0; nt < 4; ++nt) {
      const int c = ct * 64 + 16 * nt + qn;
#pragma unroll
      for (int r = 0; r < 4; ++r)
        El[mloc + r][c] =
            f2bf(resd[((long)mblk * 64 + mloc + r) * KD + c] + sc * acc[nt][r]);
    }
    __syncthreads();
  }

  // phase 3: qkv from El
  for (int wt = 0; wt < 9; ++wt) {
    {
      const unsigned short* Wp = args.Wq[z] + ((long)wt * 64 + row) * KD + cb;
#pragma unroll
      for (int j = 0; j < 6; ++j)
        *(float4*)&Wl[row][cb + 8 * j] = *(const float4*)(Wp + 8 * j);
    }
    __syncthreads();
    f32x4 acc[4];
#pragma unroll
    for (int nt = 0; nt < 4; ++nt) acc[nt] = zero;
#pragma unroll
    for (int ks = 0; ks < 6; ++ks) {
      bf16x8 a = *(const bf16x8*)&El[16 * wv + qn][32 * ks + 8 * g];
#pragma unroll
      for (int nt = 0; nt < 4; ++nt) {
        bf16x8 bfr = *(const bf16x8*)&Wl[16 * nt + qn][32 * ks + 8 * g];
        acc[nt] = __builtin_amdgcn_mfma_f32_16x16x32_bf16(a, bfr, acc[nt], 0, 0, 0);
      }
    }
#pragma unroll
    for (int nt = 0; nt < 4; ++nt) {
      const int cg = wt * 64 + 16 * nt + qn;
      const int idx = (cg >= 384) ? 2 : ((cg >= 192) ? 1 : 0);
      const int cc = cg - idx * KD;
      const int h = cc >> 5, d = cc & 31;
      const float bv = args.bias[z][cg];
      const float sca = (idx == 0) ? SC : 1.f;
      const long bwh = (long)mblk * H6 + h;
      if (idx < 2) {
        unsigned short* dst = idx ? args.dk[z] : args.dq[z];
#pragma unroll
        for (int r = 0; r < 4; ++r)
          dst[(bwh * 64 + (mloc + r)) * 32 + d] = f2bf((acc[nt][r] + bv) * sca);
      } else {  // v transposed: [b][h][d][tok]
        ushort4 p;
        p.x = f2bf(acc[nt][0] + bv);
        p.y = f2bf(acc[nt][1] + bv);
        p.z = f2bf(acc[nt][2] + bv);
        p.w = f2bf(acc[nt][3] + bv);
        *(ushort4*)&args.dv[z][(bwh * 32 + d) * 64 + mloc] = p;
      }
    }
    __syncthreads();
  }
}

// ---------------- shared softmax helper ----------------
__device__ __forceinline__ void softmax_rows2(f32x4 (&S)[4][2]) {
#pragma unroll
  for (int nt = 0; nt < 2; ++nt) {
    float mx = -3.0e38f;
#pragma unroll
    for (int mt = 0; mt < 4; ++mt)
#pragma unroll
      for (int r = 0; r < 4; ++r) mx = fmaxf(mx, S[mt][nt][r]);
    mx = fmaxf(mx, __shfl_xor(mx, 16));
    mx = fmaxf(mx, __shfl_xor(mx, 32));
    float sm = 0.f;
#pragma unroll
    for (int mt = 0; mt < 4; ++mt)
#pragma unroll
      for (int r = 0; r < 4; ++r) {
        float p = __expf(S[mt][nt][r] - mx);
        S[mt][nt][r] = p;
        sm += p;
      }
    sm += __shfl_xor(sm, 16);
    sm += __shfl_xor(sm, 32);
    const float inv = 1.f / sm;
#pragma unroll
    for (int mt = 0; mt < 4; ++mt)
#pragma unroll
      for (int r = 0; r < 4; ++r) S[mt][nt][r] *= inv;
  }
}

// ================= FUSED attn + proj (primary path) =================
// grid (B, 2): z=0 SA, z=1 CA. 768 threads = 12 waves; 2 waves per head
// (32 q-rows each). Attn math identical to diff_attn32; O_t/O_r staged in
// LDS; after one barrier each wave projects a 16-col output strip with
// W-frags preloaded from global (L2-hot) and float4 stores to d_out.
struct FAArgs {
  const unsigned short* q[2];
  const unsigned short* k[2];
  const unsigned short* vT[2];
  const float* lamp[2];
  const unsigned short* w[2];
  const float* pb[2];
  float* ot[2];
  float* orr[2];
  long ostride[2];
};

__global__ __launch_bounds__(768, 3) void fattn_k(
    FAArgs args, const float* __restrict__ biasw, long pstride)
{
  __shared__ short Ol[2][64][200];     // [path][q][dcol]
  __shared__ short Pl[12][32][72];     // per-wave P staging (t then r)
  const int tid = threadIdx.x;
  const int wv = tid >> 6, lane = tid & 63;
  const int qn = lane & 15, g = lane >> 4;
  const int b = blockIdx.x, z = blockIdx.y;
  const int h = wv >> 1, qoff = (wv & 1) * 32;
  const long base = ((long)b * H6 + h) * 2048;
  const unsigned short* qb = args.q[z];
  const unsigned short* kb = args.k[z];
  const unsigned short* vTb = args.vT[z];
  float lam = 1.f / (1.f + __expf(-*args.lamp[z]));
  lam = fminf(fmaxf(lam, 0.01f), 0.99f);
  const float* bh = biasw + (long)h * 4096;
  short (*pl)[72] = Pl[wv];
  const f32x4 zero = {0.f, 0.f, 0.f, 0.f};

  // ---- attention (identical math to diff_attn32) ----
  f32x4 st[4][2], sr[4][2];
#pragma unroll
  for (int mt = 0; mt < 4; ++mt)
#pragma unroll
    for (int nt = 0; nt < 2; ++nt) {
      f32x4 bv = *(const f32x4*)&bh[(qoff + 16 * nt + qn) * 64 + 16 * mt + 4 * g];
      st[mt][nt] = bv;
      sr[mt][nt] = bv;
    }
  {
    bf16x8 ka[4], qv[2];
#pragma unroll
    for (int mt = 0; mt < 4; ++mt)
      ka[mt] = *(const bf16x8*)&kb[base + (16 * mt + qn) * 32 + 8 * g];
#pragma unroll
    for (int nt = 0; nt < 2; ++nt)
      qv[nt] = *(const bf16x8*)&qb[base + (qoff + 16 * nt + qn) * 32 + 8 * g];
#pragma unroll
    for (int mt = 0; mt < 4; ++mt)
#pragma unroll
      for (int nt = 0; nt < 2; ++nt)
        st[mt][nt] = __builtin_amdgcn_mfma_f32_16x16x32_bf16(ka[mt], qv[nt], st[mt][nt], 0, 0, 0);
#pragma unroll
    for (int mt = 0; mt < 4; ++mt)
      ka[mt] = *(const bf16x8*)&kb[pstride + base + (16 * mt + qn) * 32 + 8 * g];
#pragma unroll
    for (int nt = 0; nt < 2; ++nt)
      qv[nt] = *(const bf16x8*)&qb[pstride + base + (qoff + 16 * nt + qn) * 32 + 8 * g];
#pragma unroll
    for (int mt = 0; mt < 4; ++mt)
#pragma unroll
      for (int nt = 0; nt < 2; ++nt)
        sr[mt][nt] = __builtin_amdgcn_mfma_f32_16x16x32_bf16(ka[mt], qv[nt], sr[mt][nt], 0, 0, 0);
  }
  softmax_rows2(st);
  softmax_rows2(sr);
#pragma unroll
  for (int mt = 0; mt < 4; ++mt)
#pragma unroll
    for (int nt = 0; nt < 2; ++nt)
#pragma unroll
      for (int r = 0; r < 4; ++r) {
        float a = st[mt][nt][r], rr = sr[mt][nt][r];
        st[mt][nt][r] = a - lam * rr;     // dt
        sr[mt][nt][r] = rr - lam * a;     // dr
      }

#pragma unroll
  for (int p = 0; p < 2; ++p) {
    auto& P = p ? sr : st;
    // stage P into per-wave LDS (in-order DS ops: safe to reuse buffer)
#pragma unroll
    for (int mt = 0; mt < 4; ++mt)
#pragma unroll
      for (int nt = 0; nt < 2; ++nt) {
        ushort4 pk;
        pk.x = f2bf(P[mt][nt][0]); pk.y = f2bf(P[mt][nt][1]);
        pk.z = f2bf(P[mt][nt][2]); pk.w = f2bf(P[mt][nt][3]);
        *(ushort4*)&pl[16 * nt + qn][16 * mt + 4 * g] = pk;
      }
    const unsigned short* vv = p ? (vTb + pstride) : vTb;
    f32x4 oa[2][2];
#pragma unroll
    for (int i = 0; i < 2; ++i)
#pragma unroll
      for (int nt = 0; nt < 2; ++nt) oa[i][nt] = zero;
#pragma unroll
    for (int ks = 0; ks < 2; ++ks) {
      bf16x8 va0 = *(const bf16x8*)&vv[base + (0 + qn) * 64 + 32 * ks + 8 * g];
      bf16x8 va1 = *(const bf16x8*)&vv[base + (16 + qn) * 64 + 32 * ks + 8 * g];
#pragma unroll
      for (int nt = 0; nt < 2; ++nt) {
        bf16x8 pb8 = *(const bf16x8*)&pl[16 * nt + qn][32 * ks + 8 * g];
        oa[0][nt] = __builtin_amdgcn_mfma_f32_16x16x32_bf16(va0, pb8, oa[0][nt], 0, 0, 0);
        oa[1][nt] = __builtin_amdgcn_mfma_f32_16x16x32_bf16(va1, pb8, oa[1][nt], 0, 0, 0);
      }
    }
#pragma unroll
    for (int d16 = 0; d16 < 2; ++d16)
#pragma unroll
      for (int nt = 0; nt < 2; ++nt) {
        ushort4 pk;
        pk.x = f2bf(oa[d16][nt][0]); pk.y = f2bf(oa[d16][nt][1]);
        pk.z = f2bf(oa[d16][nt][2]); pk.w = f2bf(oa[d16][nt][3]);
        *(ushort4*)&Ol[p][qoff + 16 * nt + qn][h * 32 + 16 * d16 + 4 * g] = pk;
      }
  }

  // ---- proj: prefetch W frags + bias before barrier (overlap) ----
  const int cstrip = wv * 16;
  const unsigned short* wz = args.w[z];
  bf16x8 wf[6];
#pragma unroll
  for (int ks = 0; ks < 6; ++ks)
    wf[ks] = *(const bf16x8*)&wz[(long)(cstrip + qn) * KD + 32 * ks + 8 * g];
  f32x4 biasv = *(const f32x4*)&args.pb[z][cstrip + 4 * g];
  __syncthreads();

#pragma unroll
  for (int p = 0; p < 2; ++p) {
    f32x4 acc[4];
#pragma unroll
    for (int mt = 0; mt < 4; ++mt) acc[mt] = zero;
#pragma unroll
    for (int ks = 0; ks < 6; ++ks)
#pragma unroll
      for (int mt = 0; mt < 4; ++mt) {
        bf16x8 of = *(const bf16x8*)&Ol[p][16 * mt + qn][32 * ks + 8 * g];
        // A=W rows (c), B=O rows (m): D[c-local=4g+r][m-local=qn]
        acc[mt] = __builtin_amdgcn_mfma_f32_16x16x32_bf16(wf[ks], of, acc[mt], 0, 0, 0);
      }
    float* fo = (p ? args.orr[z] : args.ot[z]) + (long)b * args.ostride[z];
#pragma unroll
    for (int mt = 0; mt < 4; ++mt) {
      f32x4 res;
#pragma unroll
      for (int r = 0; r < 4; ++r) res[r] = acc[mt][r] + biasv[r];
      *(f32x4*)&fo[(long)(16 * mt + qn) * KD + cstrip + 4 * g] = res;
    }
  }
}

// ================= FALLBACK: separate attn + proj (R6-proven) =================
__device__ __forceinline__ void diff_attn32(
    const unsigned short* __restrict__ qb, const unsigned short* __restrict__ kb,
    const unsigned short* __restrict__ vTb, long pstride,
    const float* __restrict__ bh, float lam,
    unsigned short* __restrict__ o_t, unsigned short* __restrict__ o_r,
    long base, int b, int h, int qoff, int qn, int g,
    short (*Pl)[32][72])
{
  f32x4 st[4][2], sr[4][2];
#pragma unroll
  for (int mt = 0; mt < 4; ++mt)
#pragma unroll
    for (int nt = 0; nt < 2; ++nt) {
      f32x4 bv = *(const f32x4*)&bh[(qoff + 16 * nt + qn) * 64 + 16 * mt + 4 * g];
      st[mt][nt] = bv;
      sr[mt][nt] = bv;
    }
  {
    bf16x8 ka[4], qv[2];
#pragma unroll
    for (int mt = 0; mt < 4; ++mt)
      ka[mt] = *(const bf16x8*)&kb[base + (16 * mt + qn) * 32 + 8 * g];
#pragma unroll
    for (int nt = 0; nt < 2; ++nt)
      qv[nt] = *(const bf16x8*)&qb[base + (qoff + 16 * nt + qn) * 32 + 8 * g];
#pragma unroll
    for (int mt = 0; mt < 4; ++mt)
#pragma unroll
      for (int nt = 0; nt < 2; ++nt)
        st[mt][nt] = __builtin_amdgcn_mfma_f32_16x16x32_bf16(ka[mt], qv[nt], st[mt][nt], 0, 0, 0);
#pragma unroll
    for (int mt = 0; mt < 4; ++mt)
      ka[mt] = *(const bf16x8*)&kb[pstride + base + (16 * mt + qn) * 32 + 8 * g];
#pragma unroll
    for (int nt = 0; nt < 2; ++nt)
      qv[nt] = *(const bf16x8*)&qb[pstride + base + (qoff + 16 * nt + qn) * 32 + 8 * g];
#pragma unroll
    for (int mt = 0; mt < 4; ++mt)
#pragma unroll
      for (int nt = 0; nt < 2; ++nt)
        sr[mt][nt] = __builtin_amdgcn_mfma_f32_16x16x32_bf16(ka[mt], qv[nt], sr[mt][nt], 0, 0, 0);
  }
  softmax_rows2(st);
  softmax_rows2(sr);
#pragma unroll
  for (int mt = 0; mt < 4; ++mt)
#pragma unroll
    for (int nt = 0; nt < 2; ++nt) {
      ushort4 pt, pr;
#pragma unroll
      for (int r = 0; r < 4; ++r) {
        float a = st[mt][nt][r], rr = sr[mt][nt][r];
        ((unsigned short*)&pt)[r] = f2bf(a - lam * rr);
        ((unsigned short*)&pr)[r] = f2bf(rr - lam * a);
      }
      *(ushort4*)&Pl[0][16 * nt + qn][16 * mt + 4 * g] = pt;
      *(ushort4*)&Pl[1][16 * nt + qn][16 * mt + 4 * g] = pr;
    }
  const f32x4 zero = {0.f, 0.f, 0.f, 0.f};
#pragma unroll
  for (int p = 0; p < 2; ++p) {
    const unsigned short* vv = p ? (vTb + pstride) : vTb;
    unsigned short* outp = p ? o_r : o_t;
    f32x4 oa[2][2];
#pragma unroll
    for (int i = 0; i < 2; ++i)
#pragma unroll
      for (int nt = 0; nt < 2; ++nt) oa[i][nt] = zero;
#pragma unroll
    for (int ks = 0; ks < 2; ++ks) {
      bf16x8 va0 = *(const bf16x8*)&vv[base + (0 + qn) * 64 + 32 * ks + 8 * g];
      bf16x8 va1 = *(const bf16x8*)&vv[base + (16 + qn) * 64 + 32 * ks + 8 * g];
#pragma unroll
      for (int nt = 0; nt < 2; ++nt) {
        bf16x8 pb = *(const bf16x8*)&Pl[p][16 * nt + qn][32 * ks + 8 * g];
        oa[0][nt] = __builtin_amdgcn_mfma_f32_16x16x32_bf16(va0, pb, oa[0][nt], 0, 0, 0);
        oa[1][nt] = __builtin_amdgcn_mfma_f32_16x16x32_bf16(va1, pb, oa[1][nt], 0, 0, 0);
      }
    }
#pragma unroll
    for (int d16 = 0; d16 < 2; ++d16)
#pragma unroll
      for (int nt = 0; nt < 2; ++nt) {
        const int q = qoff + 16 * nt + qn;
        ushort4 pk;
        pk.x = f2bf(oa[d16][nt][0]); pk.y = f2bf(oa[d16][nt][1]);
        pk.z = f2bf(oa[d16][nt][2]); pk.w = f2bf(oa[d16][nt][3]);
        *(ushort4*)&outp[((long)b * 64 + q) * KD + h * 32 + 16 * d16 + 4 * g] = pk;
      }
  }
}

__global__ __launch_bounds__(256) void attn_k(
    const unsigned short* __restrict__ saq, const unsigned short* __restrict__ sak,
    const unsigned short* __restrict__ savT,
    const unsigned short* __restrict__ caq, const unsigned short* __restrict__ cak,
    const unsigned short* __restrict__ cavT,
    const float* __restrict__ biasw, const float* __restrict__ lsp,
    const float* __restrict__ lcp,
    unsigned short* __restrict__ o0, unsigned short* __restrict__ o1,
    unsigned short* __restrict__ o2, unsigned short* __restrict__ o3,
    long pstride)
{
  __shared__ short Pl[4][2][32][72];
  const int wv = threadIdx.x >> 6, lane = threadIdx.x & 63;
  const int qn = lane & 15, g = lane >> 4;
  const int qoff = (wv & 1) * 32;
  const int wh = blockIdx.x * 2 + (wv >> 1);
  const int b = wh / H6, h = wh - b * H6;
  const float* bh = biasw + (long)h * 4096;
  const long base = (long)wh * 2048;
  float ls = 1.f / (1.f + __expf(-*lsp));
  ls = fminf(fmaxf(ls, 0.01f), 0.99f);
  float lc = 1.f / (1.f + __expf(-*lcp));
  lc = fminf(fmaxf(lc, 0.01f), 0.99f);
  diff_attn32(saq, sak, savT, pstride, bh, ls, o0, o1, base, b, h, qoff, qn, g, Pl[wv]);
  diff_attn32(caq, cak, cavT, pstride, bh, lc, o2, o3, base, b, h, qoff, qn, g, Pl[wv]);
}

struct ProjArgs {
  const unsigned short* A[4];
  const unsigned short* W[4];
  const float* bias[4];
  float* o[4];
  long wstride[4];
};

__global__ __launch_bounds__(256) void proj_k(ProjArgs args)
{
  __shared__ short Al[64][200], Wl[64][200];
  const int tid = threadIdx.x;
  const int mblk = blockIdx.x, z = blockIdx.y;
  const int row = tid >> 2, cb = (tid & 3) * 48;
  {
    const unsigned short* A = args.A[z] + ((long)mblk * 64 + row) * KD + cb;
#pragma unroll
    for (int j = 0; j < 6; ++j)
      *(float4*)&Al[row][cb + 8 * j] = *(const float4*)(A + 8 * j);
  }
  const int lane = tid & 63, wv = tid >> 6;
  const int qn = lane & 15, g = lane >> 4;
  const int mloc = 16 * wv + 4 * g;
  const f32x4 zero = {0.f, 0.f, 0.f, 0.f};
  float* fo = args.o[z] + (long)mblk * args.wstride[z];

  for (int ct = 0; ct < 3; ++ct) {
    {
      const unsigned short* Wp = args.W[z] + ((long)ct * 64 + row) * KD + cb;
#pragma unroll
      for (int j = 0; j < 6; ++j)
        *(float4*)&Wl[row][cb + 8 * j] = *(const float4*)(Wp + 8 * j);
    }
    __syncthreads();
    f32x4 acc[4];
#pragma unroll
    for (int nt = 0; nt < 4; ++nt) acc[nt] = zero;
#pragma unroll
    for (int ks = 0; ks < 6; ++ks) {
      bf16x8 a = *(const bf16x8*)&Al[16 * wv + qn][32 * ks + 8 * g];
#pragma unroll
      for (int nt = 0; nt < 4; ++nt) {
        bf16x8 bfr = *(const bf16x8*)&Wl[16 * nt + qn][32 * ks + 8 * g];
        acc[nt] = __builtin_amdgcn_mfma_f32_16x16x32_bf16(a, bfr, acc[nt], 0, 0, 0);
      }
    }
#pragma unroll
    for (int nt = 0; nt < 4; ++nt) {
      const int c = ct * 64 + 16 * nt + qn;
      const float bv = args.bias[z][c];
#pragma unroll
      for (int r = 0; r < 4; ++r)
        fo[(long)(mloc + r) * KD + c] = acc[nt][r] + bv;
    }
    __syncthreads();
  }
}

// ---------------- host ----------------
extern "C" void kernel_launch(void* const* d_in, const int* in_sizes, int n_in,
                              void* d_out, int out_size, void* d_ws, size_t ws_size,
                              hipStream_t stream)
{
  const float* x         = (const float*)d_in[0];
  const float* y         = (const float*)d_in[1];
  const float* sa_qkv_w  = (const float*)d_in[2];
  const float* sa_qkv_b  = (const float*)d_in[3];
  const float* sa_ct_w   = (const float*)d_in[4];
  const float* sa_cr_w   = (const float*)d_in[5];
  const float* ca_q_w    = (const float*)d_in[6];
  const float* ca_q_b    = (const float*)d_in[7];
  const float* ca_kv_w   = (const float*)d_in[8];
  const float* ca_kv_b   = (const float*)d_in[9];
  const float* ca_ct_w   = (const float*)d_in[10];
  const float* ca_cr_w   = (const float*)d_in[11];
  const float* rpb       = (const float*)d_in[12];
  const float* proj_sa_w = (const float*)d_in[13];
  const float* proj_sa_b = (const float*)d_in[14];
  const float* proj_ca_w = (const float*)d_in[15];
  const float* proj_ca_b = (const float*)d_in[16];
  const float* lam_sa_p  = (const float*)d_in[17];
  const float* lam_ca_p  = (const float*)d_in[18];
  const float* sa_enh_p  = (const float*)d_in[19];
  const float* ca_enh_p  = (const float*)d_in[20];
  float* out = (float*)d_out;

  const int M = in_sizes[0] / KD;            // 65536
  const int B = M / 64;                      // 1024
  const long pstride = (long)B * H6 * 2048;  // 12,582,912 elements

  char* ws = (char*)d_ws;
  float* biasw = (float*)ws;                               // 98304 B
  float* bca = (float*)(ws + 98304);                       // 2304 B
  unsigned short* wqkv   = (unsigned short*)(ws + 100864); // 221184 B
  unsigned short* wca    = (unsigned short*)(ws + 322048); // 221184 B
  unsigned short* wct_sa = (unsigned short*)(ws + 543232);
  unsigned short* wcr_sa = (unsigned short*)(ws + 616960);
  unsigned short* wct_ca = (unsigned short*)(ws + 690688);
  unsigned short* wcr_ca = (unsigned short*)(ws + 764416);
  unsigned short* wpsa   = (unsigned short*)(ws + 838144);
  unsigned short* wpca   = (unsigned short*)(ws + 911872);

  const size_t TEN = (size_t)pstride * 4;    // bytes per qkv tensor (both paths)
  const size_t NEED = 1048576 + 6 * TEN;     // 303,038,464 B
  const bool fused = (ws_size >= NEED);

  const float SC = 0.17677669529663687f;     // 32^-0.5

  convert_k<<<dim3(433), dim3(256), 0, stream>>>(
      sa_qkv_w, sa_ct_w, sa_cr_w, ca_q_w, ca_kv_w, ca_ct_w, ca_cr_w,
      proj_sa_w, proj_ca_w, ca_q_b, ca_kv_b,
      wqkv, wct_sa, wcr_sa, wca, wct_ca, wcr_ca, wpsa, wpca, bca);
  bias_k<<<dim3(96), dim3(256), 0, stream>>>(rpb, biasw);

  if (fused) {
    long off = 1048576;
    unsigned short* saq  = (unsigned short*)(ws + off); off += TEN;
    unsigned short* sak  = (unsigned short*)(ws + off); off += TEN;
    unsigned short* savT = (unsigned short*)(ws + off); off += TEN;
    unsigned short* caq  = (unsigned short*)(ws + off); off += TEN;
    unsigned short* cak  = (unsigned short*)(ws + off); off += TEN;
    unsigned short* cavT = (unsigned short*)(ws + off);

    FQArgs fa;
    fa.Wc[0] = wcr_sa; fa.Wc[1] = wct_sa; fa.Wc[2] = wcr_ca; fa.Wc[3] = wct_ca;
    fa.Wq[0] = wqkv;   fa.Wq[1] = wqkv;   fa.Wq[2] = wca;    fa.Wq[3] = wca;
    fa.bias[0] = sa_qkv_b; fa.bias[1] = sa_qkv_b; fa.bias[2] = bca; fa.bias[3] = bca;
    fa.dq[0] = saq;  fa.dq[1] = saq + pstride;  fa.dq[2] = caq;  fa.dq[3] = caq + pstride;
    fa.dk[0] = sak;  fa.dk[1] = sak + pstride;  fa.dk[2] = cak;  fa.dk[3] = cak + pstride;
    fa.dv[0] = savT; fa.dv[1] = savT + pstride; fa.dv[2] = cavT; fa.dv[3] = cavT + pstride;
    fqkv_k<<<dim3(B, 4), dim3(256), 0, stream>>>(x, y, sa_enh_p, ca_enh_p, fa, SC);

    FAArgs aa;
    aa.q[0] = saq;  aa.q[1] = caq;
    aa.k[0] = sak;  aa.k[1] = cak;
    aa.vT[0] = savT; aa.vT[1] = cavT;
    aa.lamp[0] = lam_sa_p; aa.lamp[1] = lam_ca_p;
    aa.w[0] = wpsa; aa.w[1] = wpca;
    aa.pb[0] = proj_sa_b; aa.pb[1] = proj_ca_b;
    aa.ot[0]  = out;
    aa.orr[0] = out + (long)B * 12288;
    aa.ot[1]  = out + (long)2 * B * 12288;
    aa.orr[1] = out + (long)2 * B * 12288 + 12288;
    aa.ostride[0] = 12288;
    aa.ostride[1] = 24576;
    fattn_k<<<dim3(B, 2), dim3(768), 0, stream>>>(aa, biasw, pstride);
  } else {
    long off = 1048576;
    unsigned short* ob0 = (unsigned short*)(ws + off); off += (long)M * KD * 2;
    unsigned short* ob1 = (unsigned short*)(ws + off); off += (long)M * KD * 2;
    unsigned short* ob2 = (unsigned short*)(ws + off); off += (long)M * KD * 2;
    unsigned short* ob3 = (unsigned short*)(ws + off); off += (long)M * KD * 2;
    unsigned short* caq  = (unsigned short*)(ws + off); off += TEN;
    unsigned short* cak  = (unsigned short*)(ws + off); off += TEN;
    unsigned short* cavT = (unsigned short*)(ws + off);
    unsigned short* saq  = (unsigned short*)d_out;
    unsigned short* sak  = saq + 2 * pstride;
    unsigned short* savT = sak + 2 * pstride;

    FQArgs fa;
    fa.Wc[0] = wcr_sa; fa.Wc[1] = wct_sa; fa.Wc[2] = wcr_ca; fa.Wc[3] = wct_ca;
    fa.Wq[0] = wqkv;   fa.Wq[1] = wqkv;   fa.Wq[2] = wca;    fa.Wq[3] = wca;
    fa.bias[0] = sa_qkv_b; fa.bias[1] = sa_qkv_b; fa.bias[2] = bca; fa.bias[3] = bca;
    fa.dq[0] = saq;  fa.dq[1] = saq + pstride;  fa.dq[2] = caq;  fa.dq[3] = caq + pstride;
    fa.dk[0] = sak;  fa.dk[1] = sak + pstride;  fa.dk[2] = cak;  fa.dk[3] = cak + pstride;
    fa.dv[0] = savT; fa.dv[1] = savT + pstride; fa.dv[2] = cavT; fa.dv[3] = cavT + pstride;
    fqkv_k<<<dim3(B, 4), dim3(256), 0, stream>>>(x, y, sa_enh_p, ca_enh_p, fa, SC);

    attn_k<<<dim3(B * H6 / 2), dim3(256), 0, stream>>>(saq, sak, savT, caq, cak, cavT,
                                                       biasw, lam_sa_p, lam_ca_p,
                                                       ob0, ob1, ob2, ob3, pstride);

    ProjArgs pa;
    pa.A[0] = ob0; pa.A[1] = ob1; pa.A[2] = ob2; pa.A[3] = ob3;
    pa.W[0] = wpsa; pa.W[1] = wpsa; pa.W[2] = wpca; pa.W[3] = wpca;
    pa.bias[0] = proj_sa_b; pa.bias[1] = proj_sa_b; pa.bias[2] = proj_ca_b; pa.bias[3] = proj_ca_b;
    pa.o[0] = out;                       pa.wstride[0] = 12288;
    pa.o[1] = out + (long)B * 12288;     pa.wstride[1] = 12288;
    pa.o[2] = out + (long)2 * B * 12288; pa.wstride[2] = 24576;
    pa.o[3] = out + (long)2 * B * 12288 + 12288; pa.wstride[3] = 24576;
    proj_k<<<dim3(B, 4), dim3(256), 0, stream>>>(pa);
  }
}